// Round 4
// baseline (175.270 us; speedup 1.0000x reference)
//
#include <hip/hip_runtime.h>

// out[b, c, w, f] = X[b, c, f*HOP + w]  (transpose of contiguous X chunks)
// B=16, C=2, T=262144, WINDOW=1024, HOP=256, NF=1021
#define WINDOW_SZ 1024
#define HOP_SZ    256
#define NFRAMES   1021
#define T_LEN     262144

#define WT 32      // w rows per block: full 128B input lines, full output rows
#define FC 256     // frames per chunk (4 chunks per block)
#define LDS_S 261  // ==1 (mod 4): aligned ds_read_b128; ==5 (mod 32): <=2-way write conflicts

__global__ __launch_bounds__(256)
void frame_transpose3(const float* __restrict__ X, float* __restrict__ out) {
    __shared__ __align__(16) float lds[WT * LDS_S];   // 33.4 KB -> 4 blocks/CU

    const int tid  = threadIdx.x;
    const int w0   = blockIdx.x * WT;   // 32 w-tiles
    const int bc   = blockIdx.y;        // 32 slabs

    const float* Xb = X + (size_t)bc * T_LEN + w0;
    float* Ob = out + ((size_t)bc * WINDOW_SZ + w0) * (size_t)NFRAMES;

    const int j    = tid & 7;    // w-quad 0..7 (covers 32 w = one 128B line per f)
    const int fb   = tid >> 3;   // 0..31
    const int lane = tid & 63;
    const int wv   = tid >> 6;   // wave 0..3

    for (int fc = 0; fc < NFRAMES; fc += FC) {
        const int flim = min(FC, NFRAMES - fc);   // 256,256,256,253

        // ---- load: 256 f x 32 w. Per wave-instr: 8 f-rows x 128B full lines.
        //      8 independent float4 loads per thread (ILP). LDS scatter <=2-way.
#pragma unroll
        for (int p = 0; p < 8; ++p) {
            const int f = fb + 32 * p;
            if (f < flim) {
                const float4 v = *(const float4*)(Xb + (size_t)(fc + f) * HOP_SZ + 4 * j);
                float* dst = &lds[(4 * j) * LDS_S + f];
                dst[0 * LDS_S] = v.x;
                dst[1 * LDS_S] = v.y;
                dst[2 * LDS_S] = v.z;
                dst[3 * LDS_S] = v.w;
            }
        }
        __syncthreads();

        // ---- store: 32 full rows, 8 per wave; wave-uniform alignment peel,
        //      aligned ds_read_b128 + aligned global dwordx4 (1KB/instr).
#pragma unroll
        for (int r = 0; r < 8; ++r) {
            const int w = wv * 8 + r;
            const int p = (4 - ((w0 + w) & 3)) & 3;   // first 16B-aligned local f
            float* orow = Ob + (size_t)w * NFRAMES + fc;
            const float* lrow = &lds[w * LDS_S];

            const int fv = p + 4 * lane;
            if (fv + 4 <= flim) {
                *(float4*)(orow + fv) = *(const float4*)(lrow + fv);  // both 16B-aligned
            }
            // head (p floats) + tail ((flim-p)&3 floats): <=6 lanes scalar
            const int nt = (flim - p) & 3;
            const int ts = flim - nt;
            int fs = -1;
            if (lane < p) fs = lane;
            else if (lane < p + nt) fs = ts + (lane - p);
            if (fs >= 0) orow[fs] = lrow[fs];
        }
        __syncthreads();
    }
}

extern "C" void kernel_launch(void* const* d_in, const int* in_sizes, int n_in,
                              void* d_out, int out_size, void* d_ws, size_t ws_size,
                              hipStream_t stream) {
    const float* X = (const float*)d_in[0];
    float* out = (float*)d_out;

    dim3 block(256, 1, 1);
    dim3 grid(WINDOW_SZ / WT,   // 32 w-tiles (tiles 8 apart share input lines & XCD)
              32,               // b*c slabs
              1);
    frame_transpose3<<<grid, block, 0, stream>>>(X, out);
}